// Round 12
// baseline (2315.470 us; speedup 1.0000x reference)
//
#include <hip/hip_runtime.h>

#define NN 100000
#define NE 1250000
#define NB 2048
#define NZB 391    // zstat blocks (391*256 = 100096 >= NN)
#define NBK 196    // dst buckets of 512 nodes (196*512 = 100352 >= NN)
#define BCAP 7168  // bucket capacity (mean 6400, sigma ~80 -> +9.6 sigma)
#define ARND 2048  // edges per bucketA block
#define NAB 611    // bucketA blocks = ceil(NE/ARND)

typedef __attribute__((ext_vector_type(8))) short short8;
typedef __attribute__((ext_vector_type(4))) float floatx4;

__device__ inline unsigned short f2bf(float f) {
    unsigned u = __float_as_uint(f);
    u = u + 0x7fffu + ((u >> 16) & 1u);   // RNE
    return (unsigned short)(u >> 16);
}
__device__ inline float bf2f(unsigned short h) {
    return __uint_as_float(((unsigned)h) << 16);
}

// ---- prep: wcvt + bucketA + atom_encode merged (independent workloads,
// block-uniform branch -> barriers safe; saves 2 launches + serialization) ----
__launch_bounds__(256)
__global__ void prep(const int* __restrict__ ei, const int* __restrict__ ea,
                     int* __restrict__ bcnt, unsigned long long* __restrict__ bbuf,
                     const float* __restrict__ atom_emb, const int* __restrict__ x_feat,
                     float* __restrict__ h, unsigned short* __restrict__ h16,
                     const float* __restrict__ W1, const float* __restrict__ W2,
                     unsigned short* __restrict__ w1h, unsigned short* __restrict__ w2h) {
    __shared__ int cnt[256], inc[256], cur[256], gpos[256];
    __shared__ unsigned long long buf[ARND];
    __shared__ unsigned short bos[ARND];
    int tid = threadIdx.x;
    int bid = blockIdx.x;
    if (bid < NAB) {
        // ---- bucketA: coalesced edge read -> LDS sort by bucket (dst>>9) ->
        // per-bucket global reservation -> contiguous segment flush ----
        cnt[tid] = 0; cur[tid] = 0;
        __syncthreads();
        int base = bid * ARND;
        unsigned long long rec[8]; int bb[8];
        #pragma unroll
        for (int i = 0; i < 8; i++) {
            int e = base + i * 256 + tid;
            if (e < NE) {
                int src = ei[e];
                int dst = ei[NE + e];
                unsigned at = (unsigned)(ea[e * 3] | (ea[e * 3 + 1] << 3) | (ea[e * 3 + 2] << 6));
                rec[i] = ((unsigned long long)(unsigned)dst << 32)
                       | (unsigned)src | (at << 17);
                bb[i] = dst >> 9;
                atomicAdd(&cnt[bb[i]], 1);
            } else bb[i] = -1;
        }
        __syncthreads();
        int v = cnt[tid];
        inc[tid] = v;
        __syncthreads();
        for (int d = 1; d < 256; d <<= 1) {
            int t = (tid >= d) ? inc[tid - d] : 0;
            __syncthreads();
            inc[tid] += t;
            __syncthreads();
        }
        if (v > 0) gpos[tid] = atomicAdd(&bcnt[tid], v);
        __syncthreads();
        #pragma unroll
        for (int i = 0; i < 8; i++) {
            if (bb[i] >= 0) {
                int b = bb[i];
                int p = atomicAdd(&cur[b], 1);
                int slot = (inc[b] - cnt[b]) + p;
                buf[slot] = rec[i];
                bos[slot] = (unsigned short)b;
            }
        }
        __syncthreads();
        int nval = inc[255];
        for (int s = tid; s < nval; s += 256) {
            int b = bos[s];
            int off = s - (inc[b] - cnt[b]);
            bbuf[(size_t)b * BCAP + gpos[b] + off] = buf[s];
        }
    } else if (bid < NAB + 6250) {
        // ---- atom_encode: h[n][d] = sum_f atom_emb[f][x_feat[n][f]][d] ----
        int id = (bid - NAB) * 256 + tid;     // NN*16 exact
        int n = id >> 4, q = id & 15;
        floatx4 acc = {0.f, 0.f, 0.f, 0.f};
        for (int f = 0; f < 9; f++) {
            int vv = x_feat[n * 9 + f];
            const floatx4* p = (const floatx4*)(atom_emb + (size_t)(f * 128 + vv) * 64);
            acc += p[q];
        }
        ((floatx4*)h)[(size_t)n * 16 + q] = acc;
        ushort4 hv;
        hv.x = f2bf(acc[0]); hv.y = f2bf(acc[1]); hv.z = f2bf(acc[2]); hv.w = f2bf(acc[3]);
        ((ushort4*)h16)[(size_t)n * 16 + q] = hv;
    } else {
        // ---- wcvt: weights -> bf16 transposed ----
        int id = (bid - NAB - 6250) * 256 + tid;   // 0..65535
        if (id < 32768) {
            int l = id >> 13, rem = id & 8191, c = rem >> 6, k = rem & 63;
            w1h[id] = f2bf(W1[l * 8192 + k * 128 + c]);
        } else {
            int id2 = id - 32768;
            int l = id2 >> 13, rem = id2 & 8191, c = rem >> 7, k = rem & 127;
            w2h[id2] = f2bf(W2[l * 8192 + k * 64 + c]);
        }
    }
}

// Pass B: one block per bucket. Stage records in LDS -> count per node ->
// scan -> csr (inclusive ends) -> scatter in 8 SRC-TILE passes (src>>14 order
// within each node's segment).
__launch_bounds__(256)
__global__ void bucketB(const int* __restrict__ bcnt,
                        const unsigned long long* __restrict__ bbuf,
                        int* __restrict__ csr, unsigned* __restrict__ epack) {
    __shared__ int c[512], cs[512], s[256], bp[256], sh[1];
    __shared__ unsigned long long fl[BCAP];   // 57344 B; grid=196 -> 1 block/CU
    int tid = threadIdx.x;
    int b = blockIdx.x;
    bp[tid] = (tid < NBK) ? bcnt[tid] : 0;
    c[tid] = 0; c[256 + tid] = 0;
    __syncthreads();
    for (int d = 1; d < 256; d <<= 1) {   // inclusive scan of bucket totals
        int t = (tid >= d) ? bp[tid - d] : 0;
        __syncthreads();
        bp[tid] += t;
        __syncthreads();
    }
    int gbase = b ? bp[b - 1] : 0;
    int cnt = bcnt[b];
    const unsigned long long* f = bbuf + (size_t)b * BCAP;
    int n0 = b << 9;
    for (int i = tid; i < cnt; i += 256) {
        unsigned long long v = f[i];
        fl[i] = v;
        atomicAdd(&c[(int)(v >> 32) - n0], 1);
    }
    __syncthreads();
    cs[tid] = c[tid]; cs[256 + tid] = c[256 + tid];
    // inclusive scan of c[0..511] (two 256-wide halves)
    s[tid] = c[tid];
    __syncthreads();
    for (int d = 1; d < 256; d <<= 1) {
        int t = (tid >= d) ? s[tid - d] : 0;
        __syncthreads();
        s[tid] += t;
        __syncthreads();
    }
    c[tid] = s[tid];
    if (tid == 255) sh[0] = s[255];
    __syncthreads();
    s[tid] = c[256 + tid];
    __syncthreads();
    for (int d = 1; d < 256; d <<= 1) {
        int t = (tid >= d) ? s[tid - d] : 0;
        __syncthreads();
        s[tid] += t;
        __syncthreads();
    }
    c[256 + tid] = s[tid] + sh[0];
    __syncthreads();
    int nn = NN - n0; if (nn > 512) nn = 512;
    for (int i = tid; i < 512; i += 256) {
        int start = gbase + c[i] - cs[i];
        if (i < nn) csr[n0 + i] = gbase + c[i];   // inclusive end (gather's contract)
        cs[i] = start;                            // reuse as cursor
    }
    __syncthreads();
    // 8 ordered tile passes (src>>14); barrier between passes preserves order.
    for (int t = 0; t < 8; t++) {
        for (int i = tid; i < cnt; i += 256) {
            unsigned long long v = fl[i];
            if ((int)((v & 0x1FFFFu) >> 14) == t) {
                int idx = (int)(v >> 32) - n0;
                int p = atomicAdd(&cs[idx], 1);
                epack[p] = (unsigned)v;
            }
        }
        __syncthreads();
    }
}

// agg[n] = (1+eps)*h[n] + sum_{e: dst==n} relu(h[src_e] + bond(e))
#define PROC(hh, rr, A)                                                       \
    {                                                                         \
        floatx4 m = {bf2f(hh.x), bf2f(hh.y), bf2f(hh.z), bf2f(hh.w)};         \
        if (HASBN) {                                                          \
            m[0] = fmaxf(cav[0] * m[0] + cbv[0], 0.f);                        \
            m[1] = fmaxf(cav[1] * m[1] + cbv[1], 0.f);                        \
            m[2] = fmaxf(cav[2] * m[2] + cbv[2], 0.f);                        \
            m[3] = fmaxf(cav[3] * m[3] + cbv[3], 0.f);                        \
        }                                                                     \
        m += beq[((rr >> 17) & 7u) * 16 + q];                                 \
        m += beq[(8 + ((rr >> 20) & 7u)) * 16 + q];                           \
        m += beq[(16 + ((rr >> 23) & 7u)) * 16 + q];                          \
        A[0] += fmaxf(m[0], 0.f);                                             \
        A[1] += fmaxf(m[1], 0.f);                                             \
        A[2] += fmaxf(m[2], 0.f);                                             \
        A[3] += fmaxf(m[3], 0.f);                                             \
    }

template <bool HASBN>
__global__ void gather_k(const float* __restrict__ x, const unsigned short* __restrict__ x16,
                         const float* __restrict__ bond_emb,
                         const float* __restrict__ eps, const int* __restrict__ csr,
                         const unsigned* __restrict__ epack, int l,
                         const float* __restrict__ stats, const float* __restrict__ bn_g,
                         const float* __restrict__ bn_b, float* __restrict__ agg) {
    __shared__ float be[24 * 64];
    __shared__ float ca[64], cb[64];
    int tid = threadIdx.x;
    const float* bsrc = bond_emb + (size_t)l * 1536;
    for (int i = tid; i < 1536; i += 256) be[i] = bsrc[i];
    if (tid < 64) {
        if (HASBN) {
            float s = 0.f, ss = 0.f;
            for (int j = 0; j < 8; j++) {
                s  += stats[j * 128 + tid];
                ss += stats[j * 128 + 64 + tid];
            }
            float mean = s / NN;
            float var  = ss / NN - mean * mean;
            float a = bn_g[(l - 1) * 64 + tid] * rsqrtf(var + 1e-5f);
            ca[tid] = a;
            cb[tid] = bn_b[(l - 1) * 64 + tid] - mean * a;
        } else {
            ca[tid] = 1.f; cb[tid] = 0.f;
        }
    }
    __syncthreads();
    int id = blockIdx.x * 256 + tid;           // NN*16 exact
    int n = id >> 4, q = id & 15;
    float s = 1.0f + eps[l];
    floatx4 cav = *(const floatx4*)&ca[q * 4];
    floatx4 cbv = *(const floatx4*)&cb[q * 4];
    floatx4 xv = ((const floatx4*)x)[(size_t)n * 16 + q];
    if (HASBN) {
        xv[0] = fmaxf(cav[0] * xv[0] + cbv[0], 0.f);
        xv[1] = fmaxf(cav[1] * xv[1] + cbv[1], 0.f);
        xv[2] = fmaxf(cav[2] * xv[2] + cbv[2], 0.f);
        xv[3] = fmaxf(cav[3] * xv[3] + cbv[3], 0.f);
    }
    floatx4 acc = xv * s;
    floatx4 accB = {0.f, 0.f, 0.f, 0.f};
    int k0 = n ? csr[n - 1] : 0;
    int k1 = csr[n];
    const floatx4* beq = (const floatx4*)be;
    const ushort4* xq = (const ushort4*)x16;
    int k = k0;
    for (; k + 3 < k1; k += 4) {
        unsigned r0 = epack[k];
        unsigned r1 = epack[k + 1];
        unsigned r2 = epack[k + 2];
        unsigned r3 = epack[k + 3];
        ushort4 h0 = xq[(size_t)(r0 & 0x1FFFFu) * 16 + q];
        ushort4 h1 = xq[(size_t)(r1 & 0x1FFFFu) * 16 + q];
        ushort4 h2 = xq[(size_t)(r2 & 0x1FFFFu) * 16 + q];
        ushort4 h3 = xq[(size_t)(r3 & 0x1FFFFu) * 16 + q];
        __builtin_amdgcn_sched_barrier(0);   // pin: no load sinks below here
        PROC(h0, r0, acc)
        PROC(h1, r1, accB)
        PROC(h2, r2, acc)
        PROC(h3, r3, accB)
    }
    for (; k < k1; k++) {
        unsigned r0 = epack[k];
        ushort4 h0 = xq[(size_t)(r0 & 0x1FFFFu) * 16 + q];
        PROC(h0, r0, acc)
    }
    acc += accB;
    ((floatx4*)agg)[(size_t)n * 16 + q] = acc;
}

#define MFMA __builtin_amdgcn_mfma_f32_16x16x32_bf16

// Gram pass + (last block) bn1 coefficient computation.
// Partials accumulate into G via device-scope fp32 atomics; after a threadfence
// + per-layer counter, the LAST block stages rounded W1 in LDS and computes
// cab[256] directly (bn1stat kernel deleted -> 4 fewer launches).
#define ZS 264   // LDS stride in shorts (256 + 8 pad)
__launch_bounds__(256)
__global__ void zstat(const float* __restrict__ z, float* __restrict__ G,
                      float* __restrict__ zsum,
                      const float* __restrict__ W1, const float* __restrict__ b1,
                      const float* __restrict__ bn_g, const float* __restrict__ bn_b,
                      float* __restrict__ cab, int* __restrict__ zcnt, int l) {
    __shared__ char smem[67584];
    unsigned short* zh = (unsigned short*)smem;            // 64 x ZS
    unsigned short* zl = zh + 64 * ZS;
    int tid = threadIdx.x;
    int c2 = tid & 31;            // col-pair id
    int nof = tid >> 5;           // node sub-offset 0..7
    int wv = tid >> 6, lane = tid & 63, m = lane & 15, qd = lane >> 4;
    float2 csum = make_float2(0.f, 0.f);
    floatx4 acc[8];               // 4 j-tiles x {hh, hl}
    for (int t = 0; t < 8; t++) acc[t] = (floatx4){0.f, 0.f, 0.f, 0.f};
    int base = blockIdx.x * 256;
    for (int it = 0; it < 32; it++) {
        int n = it * 8 + nof;
        int node = base + n;
        float2 v = make_float2(0.f, 0.f);
        if (node < NN) v = ((const float2*)z)[(size_t)node * 32 + c2];
        csum.x += v.x; csum.y += v.y;
        unsigned short hx = f2bf(v.x), hy = f2bf(v.y);
        zh[(2 * c2) * ZS + n] = hx;
        zh[(2 * c2 + 1) * ZS + n] = hy;
        zl[(2 * c2) * ZS + n] = f2bf(v.x - bf2f(hx));
        zl[(2 * c2 + 1) * ZS + n] = f2bf(v.y - bf2f(hy));
    }
    __syncthreads();
    for (int kc = 0; kc < 8; kc++) {
        short8 ah = *(const short8*)&zh[(wv * 16 + m) * ZS + kc * 32 + qd * 8];
        for (int j = 0; j < 4; j++) {
            short8 bh = *(const short8*)&zh[(j * 16 + m) * ZS + kc * 32 + qd * 8];
            short8 bl = *(const short8*)&zl[(j * 16 + m) * ZS + kc * 32 + qd * 8];
            acc[j * 2]     = MFMA(ah, bh, acc[j * 2], 0, 0, 0);
            acc[j * 2 + 1] = MFMA(ah, bl, acc[j * 2 + 1], 0, 0, 0);
        }
    }
    for (int j = 0; j < 4; j++)
        for (int r = 0; r < 4; r++) {
            int idx = (wv * 16 + qd * 4 + r) * 64 + j * 16 + m;
            atomicAdd(&G[idx], acc[j * 2][r]);
            atomicAdd(&G[4096 + idx], acc[j * 2 + 1][r]);
        }
    __syncthreads();               // all LDS reads done before overlay
    float* red = (float*)smem;
    red[tid] = csum.x; red[256 + tid] = csum.y;
    __syncthreads();
    if (tid < 32) {
        float sx = 0.f, sy = 0.f;
        for (int k = 0; k < 8; k++) { sx += red[k * 32 + tid]; sy += red[256 + k * 32 + tid]; }
        atomicAdd(&zsum[2 * tid], sx);
        atomicAdd(&zsum[2 * tid + 1], sy);
    }
    // ---- last-block bn1 coefficient tail ----
    __threadfence();               // this block's atomics globally visible
    int* flag = (int*)(smem + 2048);
    if (tid == 0) flag[0] = atomicAdd(zcnt, 1);
    __syncthreads();
    if (flag[0] != NZB - 1) return;
    __threadfence();               // acquire: all other blocks' atomics visible
    float* wcs = (float*)(smem + 4096);   // [64 k][128 c] rounded W1, 32 KB
    const float* W1p = W1 + l * 8192;
    for (int i2 = tid; i2 < 8192; i2 += 256) wcs[i2] = bf2f(f2bf(W1p[i2]));
    __syncthreads();
    int c = tid >> 1, hh = tid & 1;
    const volatile float* Gv = G;         // bypass L1 (atomic-written data)
    float qq = 0.f;
    for (int i = hh * 32; i < hh * 32 + 32; i++) {
        float wi = wcs[i * 128 + c];
        for (int j = 0; j < 64; j++) {
            float g0 = Gv[i * 64 + j];
            float g1 = Gv[4096 + i * 64 + j];
            qq += wi * wcs[j * 128 + c] * (g0 + 2.f * g1);
        }
    }
    qq += __shfl_xor(qq, 1);
    if (hh == 0) {
        const volatile float* zs = zsum;
        float s1 = 0.f;
        for (int kk = 0; kk < 64; kk++) s1 += zs[kk] * wcs[kk * 128 + c];
        float bc = b1[l * 128 + c];
        double mean = ((double)s1 + (double)NN * (double)bc) / (double)NN;
        double ex2  = ((double)qq + 2.0 * (double)bc * (double)s1
                       + (double)NN * (double)bc * (double)bc) / (double)NN;
        float var = (float)(ex2 - mean * mean);
        float a = bn_g[l * 128 + c] * rsqrtf(var + 1e-5f);
        cab[c] = a;
        cab[128 + c] = bn_b[l * 128 + c] - (float)mean * a + a * bc;
    }
}

// Fused MLP, barrier-minimal (unchanged, measured ~28us):
#define RS 140
__launch_bounds__(256, 4)
__global__ void mlp_fused(const float* __restrict__ z,
                          const unsigned short* __restrict__ w1h,
                          const unsigned short* __restrict__ w2h,
                          const float* __restrict__ b2,
                          const float* __restrict__ cab, int l,
                          float* __restrict__ t2, unsigned short* __restrict__ t216,
                          float* __restrict__ s2f) {
    __shared__ unsigned short smem[4 * 2 * 16 * RS];   // 35840 B -> 4 blocks/CU
    int tid = threadIdx.x;
    int wv = tid >> 6, lane = tid & 63, m = lane & 15, qd = lane >> 4;
    int base = blockIdx.x * 64;
    unsigned short* rbh = smem + wv * (2 * 16 * RS);   // wave-private
    unsigned short* rbl = rbh + 16 * RS;

    int row = base + wv * 16 + m;
    floatx4 z0a = {0.f, 0.f, 0.f, 0.f}, z0b = z0a, z1a = z0a, z1b = z0a;
    if (row < NN) {
        const floatx4* zp = (const floatx4*)z + (size_t)row * 16;
        z0a = zp[qd * 2];
        z0b = zp[qd * 2 + 1];
        z1a = zp[8 + qd * 2];
        z1b = zp[8 + qd * 2 + 1];
    }
    short8 ah0, al0, ah1, al1;
    for (int j = 0; j < 4; j++) {
        unsigned short h;
        h = f2bf(z0a[j]); ah0[j] = (short)h; al0[j] = (short)f2bf(z0a[j] - bf2f(h));
        h = f2bf(z0b[j]); ah0[4 + j] = (short)h; al0[4 + j] = (short)f2bf(z0b[j] - bf2f(h));
        h = f2bf(z1a[j]); ah1[j] = (short)h; al1[j] = (short)f2bf(z1a[j] - bf2f(h));
        h = f2bf(z1b[j]); ah1[4 + j] = (short)h; al1[4 + j] = (short)f2bf(z1b[j] - bf2f(h));
    }

    float caT[8], cbT[8];
    #pragma unroll
    for (int t = 0; t < 8; t++) {
        caT[t] = cab[t * 16 + m];
        cbT[t] = cab[128 + t * 16 + m];
    }

    const unsigned short* w1p = w1h + l * 8192;
    floatx4 acc1[8];
    #pragma unroll
    for (int t = 0; t < 8; t++) {
        const unsigned short* wp = w1p + (t * 16 + m) * 64;
        short8 bh0 = *(const short8*)(wp + qd * 8);
        short8 bh1 = *(const short8*)(wp + 32 + qd * 8);
        floatx4 c0 = {0.f, 0.f, 0.f, 0.f};
        c0 = MFMA(ah0, bh0, c0, 0, 0, 0);
        c0 = MFMA(al0, bh0, c0, 0, 0, 0);
        c0 = MFMA(ah1, bh1, c0, 0, 0, 0);
        c0 = MFMA(al1, bh1, c0, 0, 0, 0);
        acc1[t] = c0;
    }

    #pragma unroll
    for (int t = 0; t < 8; t++) {
        float a = caT[t], b = cbT[t];
        #pragma unroll
        for (int r = 0; r < 4; r++) {
            int rl = qd * 4 + r;
            float rv = fmaxf(a * acc1[t][r] + b, 0.f);
            unsigned short hh = f2bf(rv);
            rbh[rl * RS + t * 16 + m] = hh;
            rbl[rl * RS + t * 16 + m] = f2bf(rv - bf2f(hh));
        }
    }
    short8 ahf[4], alf[4];
    #pragma unroll
    for (int kh = 0; kh < 4; kh++) {
        ahf[kh] = *(const short8*)&rbh[m * RS + kh * 32 + qd * 8];
        alf[kh] = *(const short8*)&rbl[m * RS + kh * 32 + qd * 8];
    }

    const unsigned short* w2p = w2h + l * 8192;
    floatx4 acc2[4];
    #pragma unroll
    for (int t = 0; t < 4; t++) {
        const unsigned short* wp = w2p + (t * 16 + m) * 128;
        floatx4 c0 = {0.f, 0.f, 0.f, 0.f};
        #pragma unroll
        for (int kh = 0; kh < 4; kh++) {
            short8 bh = *(const short8*)(wp + kh * 32 + qd * 8);
            c0 = MFMA(ahf[kh], bh, c0, 0, 0, 0);
            c0 = MFMA(alf[kh], bh, c0, 0, 0, 0);
        }
        acc2[t] = c0;
    }

    float* redw = (float*)rbh;            // 512 floats, fits the wave region
    const float* bias = b2 + l * 64;
    #pragma unroll
    for (int t = 0; t < 4; t++) {
        int col = t * 16 + m;
        float bv = bias[col];
        float s = 0.f, ss = 0.f;
        #pragma unroll
        for (int r = 0; r < 4; r++) {
            int node = base + wv * 16 + qd * 4 + r;
            if (node < NN) {
                float v = acc2[t][r] + bv;
                t2[(size_t)node * 64 + col] = v;
                t216[(size_t)node * 64 + col] = f2bf(v);
                s += v; ss += v * v;
            }
        }
        redw[col * 4 + qd] = s;
        redw[256 + col * 4 + qd] = ss;
    }
    __syncthreads();                      // the only block-wide barrier
    if (tid < 64) {
        float s = 0.f, ss = 0.f;
        for (int w = 0; w < 4; w++) {
            const float* rw = (const float*)(smem + w * (2 * 16 * RS));
            for (int q = 0; q < 4; q++) {
                s  += rw[tid * 4 + q];
                ss += rw[256 + tid * 4 + q];
            }
        }
        float* dst = s2f + (blockIdx.x & 7) * 128;   // 8-way sharded contention
        atomicAdd(&dst[tid], s);
        atomicAdd(&dst[64 + tid], ss);
    }
}

__global__ void bnapply_last(const float* __restrict__ t2, const float* __restrict__ bn_g,
                             const float* __restrict__ bn_b, const float* __restrict__ s2f,
                             float* __restrict__ out, float* __restrict__ gsum,
                             float* __restrict__ gcnt, const int* __restrict__ batch) {
    __shared__ float ca[64], cb[64];
    int tid = threadIdx.x;
    if (tid < 64) {
        float s = 0.f, ss = 0.f;
        for (int j = 0; j < 8; j++) {
            s  += s2f[j * 128 + tid];
            ss += s2f[j * 128 + 64 + tid];
        }
        float mean = s / NN;
        float var  = ss / NN - mean * mean;
        float a = bn_g[3 * 64 + tid] * rsqrtf(var + 1e-5f);
        ca[tid] = a;
        cb[tid] = bn_b[3 * 64 + tid] - mean * a;
    }
    __syncthreads();
    // batch is sorted: merge runs of equal graph id before the atomics
    int c = tid & 63, nsub = tid >> 6;
    int nodebase = blockIdx.x * 64;
    float accv = 0.f, accc = 0.f;
    int curg = -1;
    for (int it = 0; it < 16; it++) {
        int node = nodebase + it * 4 + nsub;
        if (node < NN) {
            float v = ca[c] * t2[(size_t)node * 64 + c] + cb[c];
            out[(size_t)node * 64 + c] = v;
            int g = batch[node];
            if (g != curg) {
                if (curg >= 0) {
                    atomicAdd(&gsum[(size_t)curg * 64 + c], accv);
                    if (c == 0) atomicAdd(&gcnt[curg], accc);
                }
                curg = g; accv = v; accc = 1.f;
            } else {
                accv += v; accc += 1.f;
            }
        }
    }
    if (curg >= 0) {
        atomicAdd(&gsum[(size_t)curg * 64 + c], accv);
        if (c == 0) atomicAdd(&gcnt[curg], accc);
    }
}

__global__ void pool_div(const float* __restrict__ gsum, const float* __restrict__ gcnt,
                         float* __restrict__ out) {
    int id = blockIdx.x * 256 + threadIdx.x;
    int g = id >> 6;
    out[(size_t)NN * 64 + id] = gsum[id] / (gcnt[g] + 1e-9f);
}

extern "C" void kernel_launch(void* const* d_in, const int* in_sizes, int n_in,
                              void* d_out, int out_size, void* d_ws, size_t ws_size,
                              hipStream_t stream) {
    const float* atom_emb = (const float*)d_in[0];
    const float* bond_emb = (const float*)d_in[1];
    const float* eps      = (const float*)d_in[2];
    const float* W1       = (const float*)d_in[3];
    const float* b1       = (const float*)d_in[4];
    const float* bn1_g    = (const float*)d_in[5];
    const float* bn1_b    = (const float*)d_in[6];
    const float* W2       = (const float*)d_in[7];
    const float* b2       = (const float*)d_in[8];
    const float* bn2_g    = (const float*)d_in[9];
    const float* bn2_b    = (const float*)d_in[10];
    const int* x_feat     = (const int*)d_in[11];
    const int* edge_index = (const int*)d_in[12];
    const int* edge_attr  = (const int*)d_in[13];
    const int* batch      = (const int*)d_in[14];
    float* out = (float*)d_out;

    char* ws = (char*)d_ws;
    // ---- zero region (one memset) ----
    float* gsum   = (float*)ws;   ws += (size_t)NB * 64 * 4;
    float* gcnt   = (float*)ws;   ws += NB * 4;
    float* zsum   = (float*)ws;   ws += 4 * 64 * 4;
    float* G      = (float*)ws;   ws += (size_t)4 * 8192 * 4;      // per-layer [Ghh|Ghl]
    float* s2f    = (float*)ws;   ws += (size_t)4 * 8 * 128 * 4;   // per-layer 8 shards x [sum|sumsq]
    int* bcnt     = (int*)ws;     ws += 256 * 4;                   // bucket totals
    int* zcnt     = (int*)ws;     ws += 16;                        // per-layer zstat counters
    size_t zbytes = (size_t)(ws - (char*)d_ws);
    // ---- rest ----
    int* csr        = (int*)ws;       ws += (size_t)NN * 4;        // written fully by bucketB
    float* cab      = (float*)ws;     ws += 256 * 4;               // bn1 affine (reused per layer)
    unsigned* epack = (unsigned*)ws;  ws += (size_t)NE * 4;
    float* xbuf = (float*)ws;     ws += (size_t)NN * 64 * 4;   // h (l=0) / t2 (l>=1), fp32
    unsigned short* x16 = (unsigned short*)ws; ws += (size_t)NN * 64 * 2;  // bf16 mirror
    float* agg  = (float*)ws;     ws += (size_t)NN * 64 * 4;
    unsigned short* w1h = (unsigned short*)ws; ws += 32768 * 2;
    unsigned short* w2h = (unsigned short*)ws; ws += 32768 * 2;
    unsigned long long* bbuf = (unsigned long long*)ws; ws += (size_t)NBK * BCAP * 8;

    hipMemsetAsync((void*)gsum, 0, zbytes, stream);

    prep<<<NAB + 6250 + 256, 256, 0, stream>>>(edge_index, edge_attr, bcnt, bbuf,
                                               atom_emb, x_feat, xbuf, x16,
                                               W1, W2, w1h, w2h);
    bucketB<<<NBK, 256, 0, stream>>>(bcnt, bbuf, csr, epack);

    for (int l = 0; l < 4; l++) {
        if (l == 0) {
            gather_k<false><<<6250, 256, 0, stream>>>(xbuf, x16, bond_emb, eps, csr, epack, l,
                                                      nullptr, nullptr, nullptr, agg);
        } else {
            gather_k<true><<<6250, 256, 0, stream>>>(xbuf, x16, bond_emb, eps, csr, epack, l,
                                                     s2f + (size_t)(l - 1) * 1024,
                                                     bn2_g, bn2_b, agg);
        }
        float* Gl = G + (size_t)l * 8192;
        zstat<<<NZB, 256, 0, stream>>>(agg, Gl, zsum + l * 64,
                                       W1, b1, bn1_g, bn1_b, cab, zcnt + l, l);
        mlp_fused<<<1563, 256, 0, stream>>>(agg, w1h, w2h, b2, cab, l,
                                            xbuf, x16, s2f + (size_t)l * 1024);
    }
    bnapply_last<<<1563, 256, 0, stream>>>(xbuf, bn2_g, bn2_b, s2f + (size_t)3 * 1024,
                                           out, gsum, gcnt, batch);
    pool_div<<<512, 256, 0, stream>>>(gsum, gcnt, out);
}

// Round 13
// 865.817 us; speedup vs baseline: 2.6743x; 2.6743x over previous
//
#include <hip/hip_runtime.h>

#define NN 100000
#define NE 1250000
#define NB 2048
#define NZB 391    // zstat blocks (391*256 = 100096 >= NN)
#define NBK 196    // dst buckets of 512 nodes (196*512 = 100352 >= NN)
#define BCAP 7168  // bucket capacity (mean 6400, sigma ~80 -> +9.6 sigma)
#define ARND 2048  // edges per bucketA block
#define NAB 611    // bucketA blocks = ceil(NE/ARND)

typedef __attribute__((ext_vector_type(8))) short short8;
typedef __attribute__((ext_vector_type(4))) float floatx4;

__device__ inline unsigned short f2bf(float f) {
    unsigned u = __float_as_uint(f);
    u = u + 0x7fffu + ((u >> 16) & 1u);   // RNE
    return (unsigned short)(u >> 16);
}
__device__ inline float bf2f(unsigned short h) {
    return __uint_as_float(((unsigned)h) << 16);
}

// ---- prep: wcvt + bucketA + atom_encode merged (block-uniform branch) ----
__launch_bounds__(256)
__global__ void prep(const int* __restrict__ ei, const int* __restrict__ ea,
                     int* __restrict__ bcnt, unsigned long long* __restrict__ bbuf,
                     const float* __restrict__ atom_emb, const int* __restrict__ x_feat,
                     float* __restrict__ h, unsigned short* __restrict__ h16,
                     const float* __restrict__ W1, const float* __restrict__ W2,
                     unsigned short* __restrict__ w1h, unsigned short* __restrict__ w2h) {
    __shared__ int cnt[256], inc[256], cur[256], gpos[256];
    __shared__ unsigned long long buf[ARND];
    __shared__ unsigned short bos[ARND];
    int tid = threadIdx.x;
    int bid = blockIdx.x;
    if (bid < NAB) {
        cnt[tid] = 0; cur[tid] = 0;
        __syncthreads();
        int base = bid * ARND;
        unsigned long long rec[8]; int bb[8];
        #pragma unroll
        for (int i = 0; i < 8; i++) {
            int e = base + i * 256 + tid;
            if (e < NE) {
                int src = ei[e];
                int dst = ei[NE + e];
                unsigned at = (unsigned)(ea[e * 3] | (ea[e * 3 + 1] << 3) | (ea[e * 3 + 2] << 6));
                rec[i] = ((unsigned long long)(unsigned)dst << 32)
                       | (unsigned)src | (at << 17);
                bb[i] = dst >> 9;
                atomicAdd(&cnt[bb[i]], 1);
            } else bb[i] = -1;
        }
        __syncthreads();
        int v = cnt[tid];
        inc[tid] = v;
        __syncthreads();
        for (int d = 1; d < 256; d <<= 1) {
            int t = (tid >= d) ? inc[tid - d] : 0;
            __syncthreads();
            inc[tid] += t;
            __syncthreads();
        }
        if (v > 0) gpos[tid] = atomicAdd(&bcnt[tid], v);
        __syncthreads();
        #pragma unroll
        for (int i = 0; i < 8; i++) {
            if (bb[i] >= 0) {
                int b = bb[i];
                int p = atomicAdd(&cur[b], 1);
                int slot = (inc[b] - cnt[b]) + p;
                buf[slot] = rec[i];
                bos[slot] = (unsigned short)b;
            }
        }
        __syncthreads();
        int nval = inc[255];
        for (int s = tid; s < nval; s += 256) {
            int b = bos[s];
            int off = s - (inc[b] - cnt[b]);
            bbuf[(size_t)b * BCAP + gpos[b] + off] = buf[s];
        }
    } else if (bid < NAB + 6250) {
        int id = (bid - NAB) * 256 + tid;     // NN*16 exact
        int n = id >> 4, q = id & 15;
        floatx4 acc = {0.f, 0.f, 0.f, 0.f};
        for (int f = 0; f < 9; f++) {
            int vv = x_feat[n * 9 + f];
            const floatx4* p = (const floatx4*)(atom_emb + (size_t)(f * 128 + vv) * 64);
            acc += p[q];
        }
        ((floatx4*)h)[(size_t)n * 16 + q] = acc;
        ushort4 hv;
        hv.x = f2bf(acc[0]); hv.y = f2bf(acc[1]); hv.z = f2bf(acc[2]); hv.w = f2bf(acc[3]);
        ((ushort4*)h16)[(size_t)n * 16 + q] = hv;
    } else {
        int id = (bid - NAB - 6250) * 256 + tid;   // 0..65535
        if (id < 32768) {
            int l = id >> 13, rem = id & 8191, c = rem >> 6, k = rem & 63;
            w1h[id] = f2bf(W1[l * 8192 + k * 128 + c]);
        } else {
            int id2 = id - 32768;
            int l = id2 >> 13, rem = id2 & 8191, c = rem >> 7, k = rem & 127;
            w2h[id2] = f2bf(W2[l * 8192 + k * 64 + c]);
        }
    }
}

// Pass B: one block per bucket. Stage records in LDS -> count per node ->
// scan -> csr (inclusive ends) -> scatter in 8 SRC-TILE passes.
__launch_bounds__(256)
__global__ void bucketB(const int* __restrict__ bcnt,
                        const unsigned long long* __restrict__ bbuf,
                        int* __restrict__ csr, unsigned* __restrict__ epack) {
    __shared__ int c[512], cs[512], s[256], bp[256], sh[1];
    __shared__ unsigned long long fl[BCAP];   // 57344 B; grid=196 -> 1 block/CU
    int tid = threadIdx.x;
    int b = blockIdx.x;
    bp[tid] = (tid < NBK) ? bcnt[tid] : 0;
    c[tid] = 0; c[256 + tid] = 0;
    __syncthreads();
    for (int d = 1; d < 256; d <<= 1) {   // inclusive scan of bucket totals
        int t = (tid >= d) ? bp[tid - d] : 0;
        __syncthreads();
        bp[tid] += t;
        __syncthreads();
    }
    int gbase = b ? bp[b - 1] : 0;
    int cnt = bcnt[b];
    const unsigned long long* f = bbuf + (size_t)b * BCAP;
    int n0 = b << 9;
    for (int i = tid; i < cnt; i += 256) {
        unsigned long long v = f[i];
        fl[i] = v;
        atomicAdd(&c[(int)(v >> 32) - n0], 1);
    }
    __syncthreads();
    cs[tid] = c[tid]; cs[256 + tid] = c[256 + tid];
    s[tid] = c[tid];
    __syncthreads();
    for (int d = 1; d < 256; d <<= 1) {
        int t = (tid >= d) ? s[tid - d] : 0;
        __syncthreads();
        s[tid] += t;
        __syncthreads();
    }
    c[tid] = s[tid];
    if (tid == 255) sh[0] = s[255];
    __syncthreads();
    s[tid] = c[256 + tid];
    __syncthreads();
    for (int d = 1; d < 256; d <<= 1) {
        int t = (tid >= d) ? s[tid - d] : 0;
        __syncthreads();
        s[tid] += t;
        __syncthreads();
    }
    c[256 + tid] = s[tid] + sh[0];
    __syncthreads();
    int nn = NN - n0; if (nn > 512) nn = 512;
    for (int i = tid; i < 512; i += 256) {
        int start = gbase + c[i] - cs[i];
        if (i < nn) csr[n0 + i] = gbase + c[i];   // inclusive end (gather's contract)
        cs[i] = start;                            // reuse as cursor
    }
    __syncthreads();
    for (int t = 0; t < 8; t++) {
        for (int i = tid; i < cnt; i += 256) {
            unsigned long long v = fl[i];
            if ((int)((v & 0x1FFFFu) >> 14) == t) {
                int idx = (int)(v >> 32) - n0;
                int p = atomicAdd(&cs[idx], 1);
                epack[p] = (unsigned)v;
            }
        }
        __syncthreads();
    }
}

// agg[n] = (1+eps)*h[n] + sum_{e: dst==n} relu(h[src_e] + bond(e))
#define PROC(hh, rr, A)                                                       \
    {                                                                         \
        floatx4 m = {bf2f(hh.x), bf2f(hh.y), bf2f(hh.z), bf2f(hh.w)};         \
        if (HASBN) {                                                          \
            m[0] = fmaxf(cav[0] * m[0] + cbv[0], 0.f);                        \
            m[1] = fmaxf(cav[1] * m[1] + cbv[1], 0.f);                        \
            m[2] = fmaxf(cav[2] * m[2] + cbv[2], 0.f);                        \
            m[3] = fmaxf(cav[3] * m[3] + cbv[3], 0.f);                        \
        }                                                                     \
        m += beq[((rr >> 17) & 7u) * 16 + q];                                 \
        m += beq[(8 + ((rr >> 20) & 7u)) * 16 + q];                           \
        m += beq[(16 + ((rr >> 23) & 7u)) * 16 + q];                          \
        A[0] += fmaxf(m[0], 0.f);                                             \
        A[1] += fmaxf(m[1], 0.f);                                             \
        A[2] += fmaxf(m[2], 0.f);                                             \
        A[3] += fmaxf(m[3], 0.f);                                             \
    }

template <bool HASBN>
__global__ void gather_k(const float* __restrict__ x, const unsigned short* __restrict__ x16,
                         const float* __restrict__ bond_emb,
                         const float* __restrict__ eps, const int* __restrict__ csr,
                         const unsigned* __restrict__ epack, int l,
                         const float* __restrict__ stats, const float* __restrict__ bn_g,
                         const float* __restrict__ bn_b, float* __restrict__ agg) {
    __shared__ float be[24 * 64];
    __shared__ float ca[64], cb[64];
    int tid = threadIdx.x;
    const float* bsrc = bond_emb + (size_t)l * 1536;
    for (int i = tid; i < 1536; i += 256) be[i] = bsrc[i];
    if (tid < 64) {
        if (HASBN) {
            float s = 0.f, ss = 0.f;
            for (int j = 0; j < 8; j++) {
                s  += stats[j * 128 + tid];
                ss += stats[j * 128 + 64 + tid];
            }
            float mean = s / NN;
            float var  = ss / NN - mean * mean;
            float a = bn_g[(l - 1) * 64 + tid] * rsqrtf(var + 1e-5f);
            ca[tid] = a;
            cb[tid] = bn_b[(l - 1) * 64 + tid] - mean * a;
        } else {
            ca[tid] = 1.f; cb[tid] = 0.f;
        }
    }
    __syncthreads();
    int id = blockIdx.x * 256 + tid;           // NN*16 exact
    int n = id >> 4, q = id & 15;
    float s = 1.0f + eps[l];
    floatx4 cav = *(const floatx4*)&ca[q * 4];
    floatx4 cbv = *(const floatx4*)&cb[q * 4];
    floatx4 xv = ((const floatx4*)x)[(size_t)n * 16 + q];
    if (HASBN) {
        xv[0] = fmaxf(cav[0] * xv[0] + cbv[0], 0.f);
        xv[1] = fmaxf(cav[1] * xv[1] + cbv[1], 0.f);
        xv[2] = fmaxf(cav[2] * xv[2] + cbv[2], 0.f);
        xv[3] = fmaxf(cav[3] * xv[3] + cbv[3], 0.f);
    }
    floatx4 acc = xv * s;
    floatx4 accB = {0.f, 0.f, 0.f, 0.f};
    int k0 = n ? csr[n - 1] : 0;
    int k1 = csr[n];
    const floatx4* beq = (const floatx4*)be;
    const ushort4* xq = (const ushort4*)x16;
    int k = k0;
    for (; k + 3 < k1; k += 4) {
        unsigned r0 = epack[k];
        unsigned r1 = epack[k + 1];
        unsigned r2 = epack[k + 2];
        unsigned r3 = epack[k + 3];
        ushort4 h0 = xq[(size_t)(r0 & 0x1FFFFu) * 16 + q];
        ushort4 h1 = xq[(size_t)(r1 & 0x1FFFFu) * 16 + q];
        ushort4 h2 = xq[(size_t)(r2 & 0x1FFFFu) * 16 + q];
        ushort4 h3 = xq[(size_t)(r3 & 0x1FFFFu) * 16 + q];
        __builtin_amdgcn_sched_barrier(0);   // pin: no load sinks below here
        PROC(h0, r0, acc)
        PROC(h1, r1, accB)
        PROC(h2, r2, acc)
        PROC(h3, r3, accB)
    }
    for (; k < k1; k++) {
        unsigned r0 = epack[k];
        ushort4 h0 = xq[(size_t)(r0 & 0x1FFFFu) * 16 + q];
        PROC(h0, r0, acc)
    }
    acc += accB;
    ((floatx4*)agg)[(size_t)n * 16 + q] = acc;
}

#define MFMA __builtin_amdgcn_mfma_f32_16x16x32_bf16

// Gram pass + last-block bn1 coefficient tail.
// R12 lesson: the tail must stage G cooperatively into LDS (independent loads
// across 256 threads), NOT per-thread serial volatile loops (460us disaster).
#define ZS 264   // LDS stride in shorts (256 + 8 pad)
__launch_bounds__(256)
__global__ void zstat(const float* __restrict__ z, float* __restrict__ G,
                      float* __restrict__ zsum,
                      const float* __restrict__ W1, const float* __restrict__ b1,
                      const float* __restrict__ bn_g, const float* __restrict__ bn_b,
                      float* __restrict__ cab, int* __restrict__ zcnt, int l) {
    __shared__ char smem[67584];
    unsigned short* zh = (unsigned short*)smem;            // 64 x ZS
    unsigned short* zl = zh + 64 * ZS;
    int tid = threadIdx.x;
    int c2 = tid & 31;            // col-pair id
    int nof = tid >> 5;           // node sub-offset 0..7
    int wv = tid >> 6, lane = tid & 63, m = lane & 15, qd = lane >> 4;
    float2 csum = make_float2(0.f, 0.f);
    floatx4 acc[8];               // 4 j-tiles x {hh, hl}
    for (int t = 0; t < 8; t++) acc[t] = (floatx4){0.f, 0.f, 0.f, 0.f};
    int base = blockIdx.x * 256;
    for (int it = 0; it < 32; it++) {
        int n = it * 8 + nof;
        int node = base + n;
        float2 v = make_float2(0.f, 0.f);
        if (node < NN) v = ((const float2*)z)[(size_t)node * 32 + c2];
        csum.x += v.x; csum.y += v.y;
        unsigned short hx = f2bf(v.x), hy = f2bf(v.y);
        zh[(2 * c2) * ZS + n] = hx;
        zh[(2 * c2 + 1) * ZS + n] = hy;
        zl[(2 * c2) * ZS + n] = f2bf(v.x - bf2f(hx));
        zl[(2 * c2 + 1) * ZS + n] = f2bf(v.y - bf2f(hy));
    }
    __syncthreads();
    for (int kc = 0; kc < 8; kc++) {
        short8 ah = *(const short8*)&zh[(wv * 16 + m) * ZS + kc * 32 + qd * 8];
        for (int j = 0; j < 4; j++) {
            short8 bh = *(const short8*)&zh[(j * 16 + m) * ZS + kc * 32 + qd * 8];
            short8 bl = *(const short8*)&zl[(j * 16 + m) * ZS + kc * 32 + qd * 8];
            acc[j * 2]     = MFMA(ah, bh, acc[j * 2], 0, 0, 0);
            acc[j * 2 + 1] = MFMA(ah, bl, acc[j * 2 + 1], 0, 0, 0);
        }
    }
    for (int j = 0; j < 4; j++)
        for (int r = 0; r < 4; r++) {
            int idx = (wv * 16 + qd * 4 + r) * 64 + j * 16 + m;
            atomicAdd(&G[idx], acc[j * 2][r]);
            atomicAdd(&G[4096 + idx], acc[j * 2 + 1][r]);
        }
    __syncthreads();               // all LDS reads done before overlay
    float* red = (float*)smem;
    red[tid] = csum.x; red[256 + tid] = csum.y;
    __syncthreads();
    if (tid < 32) {
        float sx = 0.f, sy = 0.f;
        for (int k = 0; k < 8; k++) { sx += red[k * 32 + tid]; sy += red[256 + k * 32 + tid]; }
        atomicAdd(&zsum[2 * tid], sx);
        atomicAdd(&zsum[2 * tid + 1], sy);
    }
    // ---- last-block bn1 coefficient tail (cooperative LDS staging) ----
    __threadfence();               // this block's atomics globally visible
    int* flag = (int*)(smem + 2048);
    if (tid == 0) flag[0] = atomicAdd(zcnt, 1);
    __syncthreads();
    if (flag[0] != NZB - 1) return;
    __threadfence();               // acquire: all other blocks' atomics visible
    float* Gc  = (float*)(smem + 4096);   // 4096 floats (g0 + 2*g1), 16 KB
    float* wcs = Gc + 4096;               // 8192 floats rounded W1, 32 KB
    float* zs  = wcs + 8192;              // 64 floats
    const volatile float* Gv = G;         // GLC loads (atomic-written data)
    for (int i2 = tid; i2 < 4096; i2 += 256)
        Gc[i2] = Gv[i2] + 2.f * Gv[4096 + i2];
    const float* W1p = W1 + l * 8192;
    for (int i2 = tid; i2 < 8192; i2 += 256) wcs[i2] = bf2f(f2bf(W1p[i2]));
    if (tid < 64) { const volatile float* zv = zsum; zs[tid] = zv[tid]; }
    __syncthreads();
    int c = tid >> 1, hh = tid & 1;
    float qq = 0.f;
    for (int i = hh * 32; i < hh * 32 + 32; i++) {
        float wi = wcs[i * 128 + c];
        #pragma unroll 8
        for (int j = 0; j < 64; j++)
            qq += wi * wcs[j * 128 + c] * Gc[i * 64 + j];
    }
    qq += __shfl_xor(qq, 1);
    if (hh == 0) {
        float s1 = 0.f;
        for (int kk = 0; kk < 64; kk++) s1 += zs[kk] * wcs[kk * 128 + c];
        float bc = b1[l * 128 + c];
        double mean = ((double)s1 + (double)NN * (double)bc) / (double)NN;
        double ex2  = ((double)qq + 2.0 * (double)bc * (double)s1
                       + (double)NN * (double)bc * (double)bc) / (double)NN;
        float var = (float)(ex2 - mean * mean);
        float a = bn_g[l * 128 + c] * rsqrtf(var + 1e-5f);
        cab[c] = a;
        cab[128 + c] = bn_b[l * 128 + c] - (float)mean * a + a * bc;
    }
}

// Fused MLP, barrier-minimal (unchanged):
#define RS 140
__launch_bounds__(256, 4)
__global__ void mlp_fused(const float* __restrict__ z,
                          const unsigned short* __restrict__ w1h,
                          const unsigned short* __restrict__ w2h,
                          const float* __restrict__ b2,
                          const float* __restrict__ cab, int l,
                          float* __restrict__ t2, unsigned short* __restrict__ t216,
                          float* __restrict__ s2f) {
    __shared__ unsigned short smem[4 * 2 * 16 * RS];   // 35840 B -> 4 blocks/CU
    int tid = threadIdx.x;
    int wv = tid >> 6, lane = tid & 63, m = lane & 15, qd = lane >> 4;
    int base = blockIdx.x * 64;
    unsigned short* rbh = smem + wv * (2 * 16 * RS);   // wave-private
    unsigned short* rbl = rbh + 16 * RS;

    int row = base + wv * 16 + m;
    floatx4 z0a = {0.f, 0.f, 0.f, 0.f}, z0b = z0a, z1a = z0a, z1b = z0a;
    if (row < NN) {
        const floatx4* zp = (const floatx4*)z + (size_t)row * 16;
        z0a = zp[qd * 2];
        z0b = zp[qd * 2 + 1];
        z1a = zp[8 + qd * 2];
        z1b = zp[8 + qd * 2 + 1];
    }
    short8 ah0, al0, ah1, al1;
    for (int j = 0; j < 4; j++) {
        unsigned short h;
        h = f2bf(z0a[j]); ah0[j] = (short)h; al0[j] = (short)f2bf(z0a[j] - bf2f(h));
        h = f2bf(z0b[j]); ah0[4 + j] = (short)h; al0[4 + j] = (short)f2bf(z0b[j] - bf2f(h));
        h = f2bf(z1a[j]); ah1[j] = (short)h; al1[j] = (short)f2bf(z1a[j] - bf2f(h));
        h = f2bf(z1b[j]); ah1[4 + j] = (short)h; al1[4 + j] = (short)f2bf(z1b[j] - bf2f(h));
    }

    float caT[8], cbT[8];
    #pragma unroll
    for (int t = 0; t < 8; t++) {
        caT[t] = cab[t * 16 + m];
        cbT[t] = cab[128 + t * 16 + m];
    }

    const unsigned short* w1p = w1h + l * 8192;
    floatx4 acc1[8];
    #pragma unroll
    for (int t = 0; t < 8; t++) {
        const unsigned short* wp = w1p + (t * 16 + m) * 64;
        short8 bh0 = *(const short8*)(wp + qd * 8);
        short8 bh1 = *(const short8*)(wp + 32 + qd * 8);
        floatx4 c0 = {0.f, 0.f, 0.f, 0.f};
        c0 = MFMA(ah0, bh0, c0, 0, 0, 0);
        c0 = MFMA(al0, bh0, c0, 0, 0, 0);
        c0 = MFMA(ah1, bh1, c0, 0, 0, 0);
        c0 = MFMA(al1, bh1, c0, 0, 0, 0);
        acc1[t] = c0;
    }

    #pragma unroll
    for (int t = 0; t < 8; t++) {
        float a = caT[t], b = cbT[t];
        #pragma unroll
        for (int r = 0; r < 4; r++) {
            int rl = qd * 4 + r;
            float rv = fmaxf(a * acc1[t][r] + b, 0.f);
            unsigned short hh = f2bf(rv);
            rbh[rl * RS + t * 16 + m] = hh;
            rbl[rl * RS + t * 16 + m] = f2bf(rv - bf2f(hh));
        }
    }
    short8 ahf[4], alf[4];
    #pragma unroll
    for (int kh = 0; kh < 4; kh++) {
        ahf[kh] = *(const short8*)&rbh[m * RS + kh * 32 + qd * 8];
        alf[kh] = *(const short8*)&rbl[m * RS + kh * 32 + qd * 8];
    }

    const unsigned short* w2p = w2h + l * 8192;
    floatx4 acc2[4];
    #pragma unroll
    for (int t = 0; t < 4; t++) {
        const unsigned short* wp = w2p + (t * 16 + m) * 128;
        floatx4 c0 = {0.f, 0.f, 0.f, 0.f};
        #pragma unroll
        for (int kh = 0; kh < 4; kh++) {
            short8 bh = *(const short8*)(wp + kh * 32 + qd * 8);
            c0 = MFMA(ahf[kh], bh, c0, 0, 0, 0);
            c0 = MFMA(alf[kh], bh, c0, 0, 0, 0);
        }
        acc2[t] = c0;
    }

    float* redw = (float*)rbh;            // 512 floats, fits the wave region
    const float* bias = b2 + l * 64;
    #pragma unroll
    for (int t = 0; t < 4; t++) {
        int col = t * 16 + m;
        float bv = bias[col];
        float s = 0.f, ss = 0.f;
        #pragma unroll
        for (int r = 0; r < 4; r++) {
            int node = base + wv * 16 + qd * 4 + r;
            if (node < NN) {
                float v = acc2[t][r] + bv;
                t2[(size_t)node * 64 + col] = v;
                t216[(size_t)node * 64 + col] = f2bf(v);
                s += v; ss += v * v;
            }
        }
        redw[col * 4 + qd] = s;
        redw[256 + col * 4 + qd] = ss;
    }
    __syncthreads();                      // the only block-wide barrier
    if (tid < 64) {
        float s = 0.f, ss = 0.f;
        for (int w = 0; w < 4; w++) {
            const float* rw = (const float*)(smem + w * (2 * 16 * RS));
            for (int q = 0; q < 4; q++) {
                s  += rw[tid * 4 + q];
                ss += rw[256 + tid * 4 + q];
            }
        }
        float* dst = s2f + (blockIdx.x & 7) * 128;   // 8-way sharded contention
        atomicAdd(&dst[tid], s);
        atomicAdd(&dst[64 + tid], ss);
    }
}

__global__ void bnapply_last(const float* __restrict__ t2, const float* __restrict__ bn_g,
                             const float* __restrict__ bn_b, const float* __restrict__ s2f,
                             float* __restrict__ out, float* __restrict__ gsum,
                             float* __restrict__ gcnt, const int* __restrict__ batch) {
    __shared__ float ca[64], cb[64];
    int tid = threadIdx.x;
    if (tid < 64) {
        float s = 0.f, ss = 0.f;
        for (int j = 0; j < 8; j++) {
            s  += s2f[j * 128 + tid];
            ss += s2f[j * 128 + 64 + tid];
        }
        float mean = s / NN;
        float var  = ss / NN - mean * mean;
        float a = bn_g[3 * 64 + tid] * rsqrtf(var + 1e-5f);
        ca[tid] = a;
        cb[tid] = bn_b[3 * 64 + tid] - mean * a;
    }
    __syncthreads();
    // batch is sorted: merge runs of equal graph id before the atomics
    int c = tid & 63, nsub = tid >> 6;
    int nodebase = blockIdx.x * 64;
    float accv = 0.f, accc = 0.f;
    int curg = -1;
    for (int it = 0; it < 16; it++) {
        int node = nodebase + it * 4 + nsub;
        if (node < NN) {
            float v = ca[c] * t2[(size_t)node * 64 + c] + cb[c];
            out[(size_t)node * 64 + c] = v;
            int g = batch[node];
            if (g != curg) {
                if (curg >= 0) {
                    atomicAdd(&gsum[(size_t)curg * 64 + c], accv);
                    if (c == 0) atomicAdd(&gcnt[curg], accc);
                }
                curg = g; accv = v; accc = 1.f;
            } else {
                accv += v; accc += 1.f;
            }
        }
    }
    if (curg >= 0) {
        atomicAdd(&gsum[(size_t)curg * 64 + c], accv);
        if (c == 0) atomicAdd(&gcnt[curg], accc);
    }
}

__global__ void pool_div(const float* __restrict__ gsum, const float* __restrict__ gcnt,
                         float* __restrict__ out) {
    int id = blockIdx.x * 256 + threadIdx.x;
    int g = id >> 6;
    out[(size_t)NN * 64 + id] = gsum[id] / (gcnt[g] + 1e-9f);
}

extern "C" void kernel_launch(void* const* d_in, const int* in_sizes, int n_in,
                              void* d_out, int out_size, void* d_ws, size_t ws_size,
                              hipStream_t stream) {
    const float* atom_emb = (const float*)d_in[0];
    const float* bond_emb = (const float*)d_in[1];
    const float* eps      = (const float*)d_in[2];
    const float* W1       = (const float*)d_in[3];
    const float* b1       = (const float*)d_in[4];
    const float* bn1_g    = (const float*)d_in[5];
    const float* bn1_b    = (const float*)d_in[6];
    const float* W2       = (const float*)d_in[7];
    const float* b2       = (const float*)d_in[8];
    const float* bn2_g    = (const float*)d_in[9];
    const float* bn2_b    = (const float*)d_in[10];
    const int* x_feat     = (const int*)d_in[11];
    const int* edge_index = (const int*)d_in[12];
    const int* edge_attr  = (const int*)d_in[13];
    const int* batch      = (const int*)d_in[14];
    float* out = (float*)d_out;

    char* ws = (char*)d_ws;
    // ---- zero region (one memset) ----
    float* gsum   = (float*)ws;   ws += (size_t)NB * 64 * 4;
    float* gcnt   = (float*)ws;   ws += NB * 4;
    float* zsum   = (float*)ws;   ws += 4 * 64 * 4;
    float* G      = (float*)ws;   ws += (size_t)4 * 8192 * 4;      // per-layer [Ghh|Ghl]
    float* s2f    = (float*)ws;   ws += (size_t)4 * 8 * 128 * 4;   // per-layer 8 shards x [sum|sumsq]
    int* bcnt     = (int*)ws;     ws += 256 * 4;                   // bucket totals
    int* zcnt     = (int*)ws;     ws += 16;                        // per-layer zstat counters
    size_t zbytes = (size_t)(ws - (char*)d_ws);
    // ---- rest ----
    int* csr        = (int*)ws;       ws += (size_t)NN * 4;        // written fully by bucketB
    float* cab      = (float*)ws;     ws += 256 * 4;               // bn1 affine (reused per layer)
    unsigned* epack = (unsigned*)ws;  ws += (size_t)NE * 4;
    float* xbuf = (float*)ws;     ws += (size_t)NN * 64 * 4;   // h (l=0) / t2 (l>=1), fp32
    unsigned short* x16 = (unsigned short*)ws; ws += (size_t)NN * 64 * 2;  // bf16 mirror
    float* agg  = (float*)ws;     ws += (size_t)NN * 64 * 4;
    unsigned short* w1h = (unsigned short*)ws; ws += 32768 * 2;
    unsigned short* w2h = (unsigned short*)ws; ws += 32768 * 2;
    unsigned long long* bbuf = (unsigned long long*)ws; ws += (size_t)NBK * BCAP * 8;

    hipMemsetAsync((void*)gsum, 0, zbytes, stream);

    prep<<<NAB + 6250 + 256, 256, 0, stream>>>(edge_index, edge_attr, bcnt, bbuf,
                                               atom_emb, x_feat, xbuf, x16,
                                               W1, W2, w1h, w2h);
    bucketB<<<NBK, 256, 0, stream>>>(bcnt, bbuf, csr, epack);

    for (int l = 0; l < 4; l++) {
        if (l == 0) {
            gather_k<false><<<6250, 256, 0, stream>>>(xbuf, x16, bond_emb, eps, csr, epack, l,
                                                      nullptr, nullptr, nullptr, agg);
        } else {
            gather_k<true><<<6250, 256, 0, stream>>>(xbuf, x16, bond_emb, eps, csr, epack, l,
                                                     s2f + (size_t)(l - 1) * 1024,
                                                     bn2_g, bn2_b, agg);
        }
        float* Gl = G + (size_t)l * 8192;
        zstat<<<NZB, 256, 0, stream>>>(agg, Gl, zsum + l * 64,
                                       W1, b1, bn1_g, bn1_b, cab, zcnt + l, l);
        mlp_fused<<<1563, 256, 0, stream>>>(agg, w1h, w2h, b2, cab, l,
                                            xbuf, x16, s2f + (size_t)l * 1024);
    }
    bnapply_last<<<1563, 256, 0, stream>>>(xbuf, bn2_g, bn2_b, s2f + (size_t)3 * 1024,
                                           out, gsum, gcnt, batch);
    pool_div<<<512, 256, 0, stream>>>(gsum, gcnt, out);
}

// Round 14
// 735.435 us; speedup vs baseline: 3.1484x; 1.1773x over previous
//
#include <hip/hip_runtime.h>

#define NN 100000
#define NE 1250000
#define NB 2048
#define NZB 391    // zstat blocks (391*256 = 100096 >= NN)
#define NBK 196    // dst buckets of 512 nodes (196*512 = 100352 >= NN)
#define BCAP 7168  // bucket capacity (mean 6400, sigma ~80 -> +9.6 sigma)
#define ARND 2048  // edges per bucketA block
#define NAB 611    // bucketA blocks = ceil(NE/ARND)

typedef __attribute__((ext_vector_type(8))) short short8;
typedef __attribute__((ext_vector_type(4))) float floatx4;

__device__ inline unsigned short f2bf(float f) {
    unsigned u = __float_as_uint(f);
    u = u + 0x7fffu + ((u >> 16) & 1u);   // RNE
    return (unsigned short)(u >> 16);
}
__device__ inline float bf2f(unsigned short h) {
    return __uint_as_float(((unsigned)h) << 16);
}

// ---- prep: wcvt + bucketA + atom_encode merged (block-uniform branch;
// independent workloads, saves 2 launches; KEPT from R11) ----
__launch_bounds__(256)
__global__ void prep(const int* __restrict__ ei, const int* __restrict__ ea,
                     int* __restrict__ bcnt, unsigned long long* __restrict__ bbuf,
                     const float* __restrict__ atom_emb, const int* __restrict__ x_feat,
                     float* __restrict__ h, unsigned short* __restrict__ h16,
                     const float* __restrict__ W1, const float* __restrict__ W2,
                     unsigned short* __restrict__ w1h, unsigned short* __restrict__ w2h) {
    __shared__ int cnt[256], inc[256], cur[256], gpos[256];
    __shared__ unsigned long long buf[ARND];
    __shared__ unsigned short bos[ARND];
    int tid = threadIdx.x;
    int bid = blockIdx.x;
    if (bid < NAB) {
        cnt[tid] = 0; cur[tid] = 0;
        __syncthreads();
        int base = bid * ARND;
        unsigned long long rec[8]; int bb[8];
        #pragma unroll
        for (int i = 0; i < 8; i++) {
            int e = base + i * 256 + tid;
            if (e < NE) {
                int src = ei[e];
                int dst = ei[NE + e];
                unsigned at = (unsigned)(ea[e * 3] | (ea[e * 3 + 1] << 3) | (ea[e * 3 + 2] << 6));
                rec[i] = ((unsigned long long)(unsigned)dst << 32)
                       | (unsigned)src | (at << 17);
                bb[i] = dst >> 9;
                atomicAdd(&cnt[bb[i]], 1);
            } else bb[i] = -1;
        }
        __syncthreads();
        int v = cnt[tid];
        inc[tid] = v;
        __syncthreads();
        for (int d = 1; d < 256; d <<= 1) {
            int t = (tid >= d) ? inc[tid - d] : 0;
            __syncthreads();
            inc[tid] += t;
            __syncthreads();
        }
        if (v > 0) gpos[tid] = atomicAdd(&bcnt[tid], v);
        __syncthreads();
        #pragma unroll
        for (int i = 0; i < 8; i++) {
            if (bb[i] >= 0) {
                int b = bb[i];
                int p = atomicAdd(&cur[b], 1);
                int slot = (inc[b] - cnt[b]) + p;
                buf[slot] = rec[i];
                bos[slot] = (unsigned short)b;
            }
        }
        __syncthreads();
        int nval = inc[255];
        for (int s = tid; s < nval; s += 256) {
            int b = bos[s];
            int off = s - (inc[b] - cnt[b]);
            bbuf[(size_t)b * BCAP + gpos[b] + off] = buf[s];
        }
    } else if (bid < NAB + 6250) {
        int id = (bid - NAB) * 256 + tid;     // NN*16 exact
        int n = id >> 4, q = id & 15;
        floatx4 acc = {0.f, 0.f, 0.f, 0.f};
        for (int f = 0; f < 9; f++) {
            int vv = x_feat[n * 9 + f];
            const floatx4* p = (const floatx4*)(atom_emb + (size_t)(f * 128 + vv) * 64);
            acc += p[q];
        }
        ((floatx4*)h)[(size_t)n * 16 + q] = acc;
        ushort4 hv;
        hv.x = f2bf(acc[0]); hv.y = f2bf(acc[1]); hv.z = f2bf(acc[2]); hv.w = f2bf(acc[3]);
        ((ushort4*)h16)[(size_t)n * 16 + q] = hv;
    } else {
        int id = (bid - NAB - 6250) * 256 + tid;   // 0..65535
        if (id < 32768) {
            int l = id >> 13, rem = id & 8191, c = rem >> 6, k = rem & 63;
            w1h[id] = f2bf(W1[l * 8192 + k * 128 + c]);
        } else {
            int id2 = id - 32768;
            int l = id2 >> 13, rem = id2 & 8191, c = rem >> 7, k = rem & 127;
            w2h[id2] = f2bf(W2[l * 8192 + k * 64 + c]);
        }
    }
}

// Pass B: one block per bucket. Stage records in LDS -> count per node ->
// scan -> csr (inclusive ends) -> scatter in 8 SRC-TILE passes.
__launch_bounds__(256)
__global__ void bucketB(const int* __restrict__ bcnt,
                        const unsigned long long* __restrict__ bbuf,
                        int* __restrict__ csr, unsigned* __restrict__ epack) {
    __shared__ int c[512], cs[512], s[256], bp[256], sh[1];
    __shared__ unsigned long long fl[BCAP];   // 57344 B; grid=196 -> 1 block/CU
    int tid = threadIdx.x;
    int b = blockIdx.x;
    bp[tid] = (tid < NBK) ? bcnt[tid] : 0;
    c[tid] = 0; c[256 + tid] = 0;
    __syncthreads();
    for (int d = 1; d < 256; d <<= 1) {   // inclusive scan of bucket totals
        int t = (tid >= d) ? bp[tid - d] : 0;
        __syncthreads();
        bp[tid] += t;
        __syncthreads();
    }
    int gbase = b ? bp[b - 1] : 0;
    int cnt = bcnt[b];
    const unsigned long long* f = bbuf + (size_t)b * BCAP;
    int n0 = b << 9;
    for (int i = tid; i < cnt; i += 256) {
        unsigned long long v = f[i];
        fl[i] = v;
        atomicAdd(&c[(int)(v >> 32) - n0], 1);
    }
    __syncthreads();
    cs[tid] = c[tid]; cs[256 + tid] = c[256 + tid];
    s[tid] = c[tid];
    __syncthreads();
    for (int d = 1; d < 256; d <<= 1) {
        int t = (tid >= d) ? s[tid - d] : 0;
        __syncthreads();
        s[tid] += t;
        __syncthreads();
    }
    c[tid] = s[tid];
    if (tid == 255) sh[0] = s[255];
    __syncthreads();
    s[tid] = c[256 + tid];
    __syncthreads();
    for (int d = 1; d < 256; d <<= 1) {
        int t = (tid >= d) ? s[tid - d] : 0;
        __syncthreads();
        s[tid] += t;
        __syncthreads();
    }
    c[256 + tid] = s[tid] + sh[0];
    __syncthreads();
    int nn = NN - n0; if (nn > 512) nn = 512;
    for (int i = tid; i < 512; i += 256) {
        int start = gbase + c[i] - cs[i];
        if (i < nn) csr[n0 + i] = gbase + c[i];   // inclusive end (gather's contract)
        cs[i] = start;                            // reuse as cursor
    }
    __syncthreads();
    for (int t = 0; t < 8; t++) {
        for (int i = tid; i < cnt; i += 256) {
            unsigned long long v = fl[i];
            if ((int)((v & 0x1FFFFu) >> 14) == t) {
                int idx = (int)(v >> 32) - n0;
                int p = atomicAdd(&cs[idx], 1);
                epack[p] = (unsigned)v;
            }
        }
        __syncthreads();
    }
}

// agg[n] = (1+eps)*h[n] + sum_{e: dst==n} relu(h[src_e] + bond(e))
#define PROC(hh, rr, A)                                                       \
    {                                                                         \
        floatx4 m = {bf2f(hh.x), bf2f(hh.y), bf2f(hh.z), bf2f(hh.w)};         \
        if (HASBN) {                                                          \
            m[0] = fmaxf(cav[0] * m[0] + cbv[0], 0.f);                        \
            m[1] = fmaxf(cav[1] * m[1] + cbv[1], 0.f);                        \
            m[2] = fmaxf(cav[2] * m[2] + cbv[2], 0.f);                        \
            m[3] = fmaxf(cav[3] * m[3] + cbv[3], 0.f);                        \
        }                                                                     \
        m += beq[((rr >> 17) & 7u) * 16 + q];                                 \
        m += beq[(8 + ((rr >> 20) & 7u)) * 16 + q];                           \
        m += beq[(16 + ((rr >> 23) & 7u)) * 16 + q];                          \
        A[0] += fmaxf(m[0], 0.f);                                             \
        A[1] += fmaxf(m[1], 0.f);                                             \
        A[2] += fmaxf(m[2], 0.f);                                             \
        A[3] += fmaxf(m[3], 0.f);                                             \
    }

template <bool HASBN>
__global__ void gather_k(const float* __restrict__ x, const unsigned short* __restrict__ x16,
                         const float* __restrict__ bond_emb,
                         const float* __restrict__ eps, const int* __restrict__ csr,
                         const unsigned* __restrict__ epack, int l,
                         const float* __restrict__ stats, const float* __restrict__ bn_g,
                         const float* __restrict__ bn_b, float* __restrict__ agg) {
    __shared__ float be[24 * 64];
    __shared__ float ca[64], cb[64];
    int tid = threadIdx.x;
    const float* bsrc = bond_emb + (size_t)l * 1536;
    for (int i = tid; i < 1536; i += 256) be[i] = bsrc[i];
    if (tid < 64) {
        if (HASBN) {
            float s = 0.f, ss = 0.f;
            for (int j = 0; j < 8; j++) {
                s  += stats[j * 128 + tid];
                ss += stats[j * 128 + 64 + tid];
            }
            float mean = s / NN;
            float var  = ss / NN - mean * mean;
            float a = bn_g[(l - 1) * 64 + tid] * rsqrtf(var + 1e-5f);
            ca[tid] = a;
            cb[tid] = bn_b[(l - 1) * 64 + tid] - mean * a;
        } else {
            ca[tid] = 1.f; cb[tid] = 0.f;
        }
    }
    __syncthreads();
    int id = blockIdx.x * 256 + tid;           // NN*16 exact
    int n = id >> 4, q = id & 15;
    float s = 1.0f + eps[l];
    floatx4 cav = *(const floatx4*)&ca[q * 4];
    floatx4 cbv = *(const floatx4*)&cb[q * 4];
    floatx4 xv = ((const floatx4*)x)[(size_t)n * 16 + q];
    if (HASBN) {
        xv[0] = fmaxf(cav[0] * xv[0] + cbv[0], 0.f);
        xv[1] = fmaxf(cav[1] * xv[1] + cbv[1], 0.f);
        xv[2] = fmaxf(cav[2] * xv[2] + cbv[2], 0.f);
        xv[3] = fmaxf(cav[3] * xv[3] + cbv[3], 0.f);
    }
    floatx4 acc = xv * s;
    floatx4 accB = {0.f, 0.f, 0.f, 0.f};
    int k0 = n ? csr[n - 1] : 0;
    int k1 = csr[n];
    const floatx4* beq = (const floatx4*)be;
    const ushort4* xq = (const ushort4*)x16;
    int k = k0;
    for (; k + 3 < k1; k += 4) {
        unsigned r0 = epack[k];
        unsigned r1 = epack[k + 1];
        unsigned r2 = epack[k + 2];
        unsigned r3 = epack[k + 3];
        ushort4 h0 = xq[(size_t)(r0 & 0x1FFFFu) * 16 + q];
        ushort4 h1 = xq[(size_t)(r1 & 0x1FFFFu) * 16 + q];
        ushort4 h2 = xq[(size_t)(r2 & 0x1FFFFu) * 16 + q];
        ushort4 h3 = xq[(size_t)(r3 & 0x1FFFFu) * 16 + q];
        __builtin_amdgcn_sched_barrier(0);   // pin: no load sinks below here
        PROC(h0, r0, acc)
        PROC(h1, r1, accB)
        PROC(h2, r2, acc)
        PROC(h3, r3, accB)
    }
    for (; k < k1; k++) {
        unsigned r0 = epack[k];
        ushort4 h0 = xq[(size_t)(r0 & 0x1FFFFu) * 16 + q];
        PROC(h0, r0, acc)
    }
    acc += accB;
    ((floatx4*)agg)[(size_t)n * 16 + q] = acc;
}

#define MFMA __builtin_amdgcn_mfma_f32_16x16x32_bf16

// Gram pass: per-block partials of G_hh, G_hl accumulate directly into G via
// fp32 atomics. NO last-block tail (R12/R13 lesson: single-block tails run at
// 1/256th parallelism -- a separate small kernel is strictly better).
#define ZS 264   // LDS stride in shorts (256 + 8 pad)
__launch_bounds__(256)
__global__ void zstat(const float* __restrict__ z, float* __restrict__ G,
                      float* __restrict__ zsum) {
    __shared__ char smem[67584];
    unsigned short* zh = (unsigned short*)smem;            // 64 x ZS
    unsigned short* zl = zh + 64 * ZS;
    int tid = threadIdx.x;
    int c2 = tid & 31;            // col-pair id
    int nof = tid >> 5;           // node sub-offset 0..7
    int wv = tid >> 6, lane = tid & 63, m = lane & 15, qd = lane >> 4;
    float2 csum = make_float2(0.f, 0.f);
    floatx4 acc[8];               // 4 j-tiles x {hh, hl}
    for (int t = 0; t < 8; t++) acc[t] = (floatx4){0.f, 0.f, 0.f, 0.f};
    int base = blockIdx.x * 256;
    for (int it = 0; it < 32; it++) {
        int n = it * 8 + nof;
        int node = base + n;
        float2 v = make_float2(0.f, 0.f);
        if (node < NN) v = ((const float2*)z)[(size_t)node * 32 + c2];
        csum.x += v.x; csum.y += v.y;
        unsigned short hx = f2bf(v.x), hy = f2bf(v.y);
        zh[(2 * c2) * ZS + n] = hx;
        zh[(2 * c2 + 1) * ZS + n] = hy;
        zl[(2 * c2) * ZS + n] = f2bf(v.x - bf2f(hx));
        zl[(2 * c2 + 1) * ZS + n] = f2bf(v.y - bf2f(hy));
    }
    __syncthreads();
    for (int kc = 0; kc < 8; kc++) {
        short8 ah = *(const short8*)&zh[(wv * 16 + m) * ZS + kc * 32 + qd * 8];
        for (int j = 0; j < 4; j++) {
            short8 bh = *(const short8*)&zh[(j * 16 + m) * ZS + kc * 32 + qd * 8];
            short8 bl = *(const short8*)&zl[(j * 16 + m) * ZS + kc * 32 + qd * 8];
            acc[j * 2]     = MFMA(ah, bh, acc[j * 2], 0, 0, 0);
            acc[j * 2 + 1] = MFMA(ah, bl, acc[j * 2 + 1], 0, 0, 0);
        }
    }
    for (int j = 0; j < 4; j++)
        for (int r = 0; r < 4; r++) {
            int idx = (wv * 16 + qd * 4 + r) * 64 + j * 16 + m;
            atomicAdd(&G[idx], acc[j * 2][r]);
            atomicAdd(&G[4096 + idx], acc[j * 2 + 1][r]);
        }
    __syncthreads();               // all LDS reads done before overlay
    float* red = (float*)smem;
    red[tid] = csum.x; red[256 + tid] = csum.y;
    __syncthreads();
    if (tid < 32) {
        float sx = 0.f, sy = 0.f;
        for (int k = 0; k < 8; k++) { sx += red[k * 32 + tid]; sy += red[256 + k * 32 + tid]; }
        atomicAdd(&zsum[2 * tid], sx);
        atomicAdd(&zsum[2 * tid + 1], sy);
    }
}

// stats1 from Gram, one block per channel c; emits bn1 affine coeffs
// cab[c] = a, cab[128+c] = b (bias b1 folded), matching GEMM1's rounded-bf16 math.
__launch_bounds__(256)
__global__ void bn1stat(const float* __restrict__ W1, const float* __restrict__ b1,
                        const float* __restrict__ G, const float* __restrict__ zsum,
                        int l, const float* __restrict__ bn_g, const float* __restrict__ bn_b,
                        float* __restrict__ cab) {
    __shared__ float wc[64];
    __shared__ float red[256];
    int c = blockIdx.x;
    int tid = threadIdx.x;
    if (tid < 64) wc[tid] = bf2f(f2bf(W1[l * 8192 + tid * 128 + c]));  // rounded W1[l][k][c]
    __syncthreads();
    float q = 0.f;
    for (int p = 0; p < 16; p++) {
        int idx = p * 256 + tid;           // coalesced over G
        int i = idx >> 6, j = idx & 63;
        q += wc[i] * wc[j] * (G[idx] + 2.f * G[4096 + idx]);
    }
    red[tid] = q;
    __syncthreads();
    for (int d = 128; d > 0; d >>= 1) {
        if (tid < d) red[tid] += red[tid + d];
        __syncthreads();
    }
    if (tid == 0) {
        float s1 = 0.f;
        for (int k = 0; k < 64; k++) s1 += zsum[k] * wc[k];
        float bc = b1[l * 128 + c];
        double mean = ((double)s1 + (double)NN * (double)bc) / (double)NN;
        double ex2  = ((double)red[0] + 2.0 * (double)bc * (double)s1
                       + (double)NN * (double)bc * (double)bc) / (double)NN;
        float var = (float)(ex2 - mean * mean);
        float a = bn_g[l * 128 + c] * rsqrtf(var + 1e-5f);
        cab[c] = a;
        cab[128 + c] = bn_b[l * 128 + c] - (float)mean * a + a * bc;
    }
}

// Fused MLP, barrier-minimal (unchanged, proven):
#define RS 140
__launch_bounds__(256, 4)
__global__ void mlp_fused(const float* __restrict__ z,
                          const unsigned short* __restrict__ w1h,
                          const unsigned short* __restrict__ w2h,
                          const float* __restrict__ b2,
                          const float* __restrict__ cab, int l,
                          float* __restrict__ t2, unsigned short* __restrict__ t216,
                          float* __restrict__ s2f) {
    __shared__ unsigned short smem[4 * 2 * 16 * RS];   // 35840 B -> 4 blocks/CU
    int tid = threadIdx.x;
    int wv = tid >> 6, lane = tid & 63, m = lane & 15, qd = lane >> 4;
    int base = blockIdx.x * 64;
    unsigned short* rbh = smem + wv * (2 * 16 * RS);   // wave-private
    unsigned short* rbl = rbh + 16 * RS;

    int row = base + wv * 16 + m;
    floatx4 z0a = {0.f, 0.f, 0.f, 0.f}, z0b = z0a, z1a = z0a, z1b = z0a;
    if (row < NN) {
        const floatx4* zp = (const floatx4*)z + (size_t)row * 16;
        z0a = zp[qd * 2];
        z0b = zp[qd * 2 + 1];
        z1a = zp[8 + qd * 2];
        z1b = zp[8 + qd * 2 + 1];
    }
    short8 ah0, al0, ah1, al1;
    for (int j = 0; j < 4; j++) {
        unsigned short h;
        h = f2bf(z0a[j]); ah0[j] = (short)h; al0[j] = (short)f2bf(z0a[j] - bf2f(h));
        h = f2bf(z0b[j]); ah0[4 + j] = (short)h; al0[4 + j] = (short)f2bf(z0b[j] - bf2f(h));
        h = f2bf(z1a[j]); ah1[j] = (short)h; al1[j] = (short)f2bf(z1a[j] - bf2f(h));
        h = f2bf(z1b[j]); ah1[4 + j] = (short)h; al1[4 + j] = (short)f2bf(z1b[j] - bf2f(h));
    }

    float caT[8], cbT[8];
    #pragma unroll
    for (int t = 0; t < 8; t++) {
        caT[t] = cab[t * 16 + m];
        cbT[t] = cab[128 + t * 16 + m];
    }

    const unsigned short* w1p = w1h + l * 8192;
    floatx4 acc1[8];
    #pragma unroll
    for (int t = 0; t < 8; t++) {
        const unsigned short* wp = w1p + (t * 16 + m) * 64;
        short8 bh0 = *(const short8*)(wp + qd * 8);
        short8 bh1 = *(const short8*)(wp + 32 + qd * 8);
        floatx4 c0 = {0.f, 0.f, 0.f, 0.f};
        c0 = MFMA(ah0, bh0, c0, 0, 0, 0);
        c0 = MFMA(al0, bh0, c0, 0, 0, 0);
        c0 = MFMA(ah1, bh1, c0, 0, 0, 0);
        c0 = MFMA(al1, bh1, c0, 0, 0, 0);
        acc1[t] = c0;
    }

    #pragma unroll
    for (int t = 0; t < 8; t++) {
        float a = caT[t], b = cbT[t];
        #pragma unroll
        for (int r = 0; r < 4; r++) {
            int rl = qd * 4 + r;
            float rv = fmaxf(a * acc1[t][r] + b, 0.f);
            unsigned short hh = f2bf(rv);
            rbh[rl * RS + t * 16 + m] = hh;
            rbl[rl * RS + t * 16 + m] = f2bf(rv - bf2f(hh));
        }
    }
    short8 ahf[4], alf[4];
    #pragma unroll
    for (int kh = 0; kh < 4; kh++) {
        ahf[kh] = *(const short8*)&rbh[m * RS + kh * 32 + qd * 8];
        alf[kh] = *(const short8*)&rbl[m * RS + kh * 32 + qd * 8];
    }

    const unsigned short* w2p = w2h + l * 8192;
    floatx4 acc2[4];
    #pragma unroll
    for (int t = 0; t < 4; t++) {
        const unsigned short* wp = w2p + (t * 16 + m) * 128;
        floatx4 c0 = {0.f, 0.f, 0.f, 0.f};
        #pragma unroll
        for (int kh = 0; kh < 4; kh++) {
            short8 bh = *(const short8*)(wp + kh * 32 + qd * 8);
            c0 = MFMA(ahf[kh], bh, c0, 0, 0, 0);
            c0 = MFMA(alf[kh], bh, c0, 0, 0, 0);
        }
        acc2[t] = c0;
    }

    float* redw = (float*)rbh;            // 512 floats, fits the wave region
    const float* bias = b2 + l * 64;
    #pragma unroll
    for (int t = 0; t < 4; t++) {
        int col = t * 16 + m;
        float bv = bias[col];
        float s = 0.f, ss = 0.f;
        #pragma unroll
        for (int r = 0; r < 4; r++) {
            int node = base + wv * 16 + qd * 4 + r;
            if (node < NN) {
                float v = acc2[t][r] + bv;
                t2[(size_t)node * 64 + col] = v;
                t216[(size_t)node * 64 + col] = f2bf(v);
                s += v; ss += v * v;
            }
        }
        redw[col * 4 + qd] = s;
        redw[256 + col * 4 + qd] = ss;
    }
    __syncthreads();                      // the only block-wide barrier
    if (tid < 64) {
        float s = 0.f, ss = 0.f;
        for (int w = 0; w < 4; w++) {
            const float* rw = (const float*)(smem + w * (2 * 16 * RS));
            for (int q = 0; q < 4; q++) {
                s  += rw[tid * 4 + q];
                ss += rw[256 + tid * 4 + q];
            }
        }
        float* dst = s2f + (blockIdx.x & 7) * 128;   // 8-way sharded contention
        atomicAdd(&dst[tid], s);
        atomicAdd(&dst[64 + tid], ss);
    }
}

__global__ void bnapply_last(const float* __restrict__ t2, const float* __restrict__ bn_g,
                             const float* __restrict__ bn_b, const float* __restrict__ s2f,
                             float* __restrict__ out, float* __restrict__ gsum,
                             float* __restrict__ gcnt, const int* __restrict__ batch) {
    __shared__ float ca[64], cb[64];
    int tid = threadIdx.x;
    if (tid < 64) {
        float s = 0.f, ss = 0.f;
        for (int j = 0; j < 8; j++) {
            s  += s2f[j * 128 + tid];
            ss += s2f[j * 128 + 64 + tid];
        }
        float mean = s / NN;
        float var  = ss / NN - mean * mean;
        float a = bn_g[3 * 64 + tid] * rsqrtf(var + 1e-5f);
        ca[tid] = a;
        cb[tid] = bn_b[3 * 64 + tid] - mean * a;
    }
    __syncthreads();
    // batch is sorted: merge runs of equal graph id before the atomics
    int c = tid & 63, nsub = tid >> 6;
    int nodebase = blockIdx.x * 64;
    float accv = 0.f, accc = 0.f;
    int curg = -1;
    for (int it = 0; it < 16; it++) {
        int node = nodebase + it * 4 + nsub;
        if (node < NN) {
            float v = ca[c] * t2[(size_t)node * 64 + c] + cb[c];
            out[(size_t)node * 64 + c] = v;
            int g = batch[node];
            if (g != curg) {
                if (curg >= 0) {
                    atomicAdd(&gsum[(size_t)curg * 64 + c], accv);
                    if (c == 0) atomicAdd(&gcnt[curg], accc);
                }
                curg = g; accv = v; accc = 1.f;
            } else {
                accv += v; accc += 1.f;
            }
        }
    }
    if (curg >= 0) {
        atomicAdd(&gsum[(size_t)curg * 64 + c], accv);
        if (c == 0) atomicAdd(&gcnt[curg], accc);
    }
}

__global__ void pool_div(const float* __restrict__ gsum, const float* __restrict__ gcnt,
                         float* __restrict__ out) {
    int id = blockIdx.x * 256 + threadIdx.x;
    int g = id >> 6;
    out[(size_t)NN * 64 + id] = gsum[id] / (gcnt[g] + 1e-9f);
}

extern "C" void kernel_launch(void* const* d_in, const int* in_sizes, int n_in,
                              void* d_out, int out_size, void* d_ws, size_t ws_size,
                              hipStream_t stream) {
    const float* atom_emb = (const float*)d_in[0];
    const float* bond_emb = (const float*)d_in[1];
    const float* eps      = (const float*)d_in[2];
    const float* W1       = (const float*)d_in[3];
    const float* b1       = (const float*)d_in[4];
    const float* bn1_g    = (const float*)d_in[5];
    const float* bn1_b    = (const float*)d_in[6];
    const float* W2       = (const float*)d_in[7];
    const float* b2       = (const float*)d_in[8];
    const float* bn2_g    = (const float*)d_in[9];
    const float* bn2_b    = (const float*)d_in[10];
    const int* x_feat     = (const int*)d_in[11];
    const int* edge_index = (const int*)d_in[12];
    const int* edge_attr  = (const int*)d_in[13];
    const int* batch      = (const int*)d_in[14];
    float* out = (float*)d_out;

    char* ws = (char*)d_ws;
    // ---- zero region (one memset) ----
    float* gsum   = (float*)ws;   ws += (size_t)NB * 64 * 4;
    float* gcnt   = (float*)ws;   ws += NB * 4;
    float* zsum   = (float*)ws;   ws += 4 * 64 * 4;
    float* G      = (float*)ws;   ws += (size_t)4 * 8192 * 4;      // per-layer [Ghh|Ghl]
    float* s2f    = (float*)ws;   ws += (size_t)4 * 8 * 128 * 4;   // per-layer 8 shards x [sum|sumsq]
    int* bcnt     = (int*)ws;     ws += 256 * 4;                   // bucket totals
    size_t zbytes = (size_t)(ws - (char*)d_ws);
    // ---- rest ----
    int* csr        = (int*)ws;       ws += (size_t)NN * 4;        // written fully by bucketB
    float* cab      = (float*)ws;     ws += 256 * 4;               // bn1 affine (reused per layer)
    unsigned* epack = (unsigned*)ws;  ws += (size_t)NE * 4;
    float* xbuf = (float*)ws;     ws += (size_t)NN * 64 * 4;   // h (l=0) / t2 (l>=1), fp32
    unsigned short* x16 = (unsigned short*)ws; ws += (size_t)NN * 64 * 2;  // bf16 mirror
    float* agg  = (float*)ws;     ws += (size_t)NN * 64 * 4;
    unsigned short* w1h = (unsigned short*)ws; ws += 32768 * 2;
    unsigned short* w2h = (unsigned short*)ws; ws += 32768 * 2;
    unsigned long long* bbuf = (unsigned long long*)ws; ws += (size_t)NBK * BCAP * 8;

    hipMemsetAsync((void*)gsum, 0, zbytes, stream);

    prep<<<NAB + 6250 + 256, 256, 0, stream>>>(edge_index, edge_attr, bcnt, bbuf,
                                               atom_emb, x_feat, xbuf, x16,
                                               W1, W2, w1h, w2h);
    bucketB<<<NBK, 256, 0, stream>>>(bcnt, bbuf, csr, epack);

    for (int l = 0; l < 4; l++) {
        if (l == 0) {
            gather_k<false><<<6250, 256, 0, stream>>>(xbuf, x16, bond_emb, eps, csr, epack, l,
                                                      nullptr, nullptr, nullptr, agg);
        } else {
            gather_k<true><<<6250, 256, 0, stream>>>(xbuf, x16, bond_emb, eps, csr, epack, l,
                                                     s2f + (size_t)(l - 1) * 1024,
                                                     bn2_g, bn2_b, agg);
        }
        float* Gl = G + (size_t)l * 8192;
        zstat<<<NZB, 256, 0, stream>>>(agg, Gl, zsum + l * 64);
        bn1stat<<<128, 256, 0, stream>>>(W1, b1, Gl, zsum + l * 64, l, bn1_g, bn1_b, cab);
        mlp_fused<<<1563, 256, 0, stream>>>(agg, w1h, w2h, b2, cab, l,
                                            xbuf, x16, s2f + (size_t)l * 1024);
    }
    bnapply_last<<<1563, 256, 0, stream>>>(xbuf, bn2_g, bn2_b, s2f + (size_t)3 * 1024,
                                           out, gsum, gcnt, batch);
    pool_div<<<512, 256, 0, stream>>>(gsum, gcnt, out);
}